// Round 9
// baseline (675.127 us; speedup 1.0000x reference)
//
#include <hip/hip_runtime.h>
#include <cmath>

#define BB 256
#define TT 512
#define NN 128
#define LN2F 0.6931471805599453f

typedef __bf16 bf16x8 __attribute__((ext_vector_type(8)));
typedef float floatx4 __attribute__((ext_vector_type(4)));

__device__ __forceinline__ float wave_max64(float v) {
    #pragma unroll
    for (int off = 32; off; off >>= 1) v = fmaxf(v, __shfl_xor(v, off));
    return v;
}
__device__ __forceinline__ float wave_sum64(float v) {
    #pragma unroll
    for (int off = 32; off; off >>= 1) v += __shfl_xor(v, off);
    return v;
}
// argmax over 128 values (lane l holds indices 2l, 2l+1); first-index tie-break.
__device__ __forceinline__ int wave_argmax128(float v0, float v1, int l) {
    float m = fmaxf(v0, v1);
    float wm = wave_max64(m);
    unsigned long long ball = __ballot(m == wm);
    int lane = __ffsll(ball) - 1;
    int idx = (v0 == wm) ? (2 * l) : (2 * l + 1);
    return __shfl(idx, lane);
}

__device__ __forceinline__ __bf16 to_bf16(float f) {   // RNE
    unsigned u = __float_as_uint(f);
    unsigned r = (u + 0x7FFFu + ((u >> 16) & 1u)) >> 16;
    union { unsigned short s; __bf16 b; } cv;
    cv.s = (unsigned short)r;
    return cv.b;
}

// Padded state layout: 32-float chunk c starts at word 36c (bank offset 4c).
__device__ __forceinline__ int padidx(int i) { return 36 * (i >> 5) + (i & 31); }

// Forward. grid = 2*BB, 512-thread blocks (8 waves), 2 blocks/CU.
// EVIDENCE (R0-R8): the barrier-to-barrier interval of a V chain is ~2232-2590
// cyc nearly independent of the work inside it (8w:2232, 16w-fused:2750,
// 16w-half-work:2590) -> latency-skeleton-bound, not issue-bound. So the
// lever is BATCHES PER CU, not work per interval.
// BLOCK MAPPING (this round): under the round-robin dispatch model (CU c
// hosts blocks c and c+256 — the same assumption the old b<->b+BB pairing
// exploited), map blocks so co-resident pairs are V+V and S+S:
//   x in [0,128)    -> V, batch 2x
//   x in [128,256)  -> S, batch 2(x-128)
//   x in [256,384)  -> V, batch 2(x-256)+1
//   x in [384,512)  -> S, batch 2(x-384)+1
// Two V blocks/CU: independent barrier domains interleave; each fills the
// other's latency stalls with its ~50%-duty issue -> ~2 batches per ~2.4-2.9k
// cyc instead of 1 per 2232. LDS 2x70KB = 140KB <= 160KB.
// Math/layout bit-identical to the proven 476us kernel.
__global__ __launch_bounds__(512, 4) void fwd_kernel(
        const float* __restrict__ em, const int* __restrict__ gtags,
        const int* __restrict__ mask, const float* __restrict__ trans,
        float* __restrict__ out_ll, float* __restrict__ out_trans,
        float* __restrict__ outp) {
    const int x = blockIdx.x;
    bool isV; int b;
    if (x < 128)      { isV = true;  b = 2 * x; }
    else if (x < 256) { isV = false; b = 2 * (x - 128); }
    else if (x < 384) { isV = true;  b = 2 * (x - 256) + 1; }
    else              { isV = false; b = 2 * (x - 384) + 1; }
    const int tid = threadIdx.x;
    const int w = tid >> 6;
    const int l = tid & 63;
    const int j = (l & 15) + 16 * w;   // column (V: unique per (w,l&15); S: same)
    const int q = l >> 4;              // V: i-chunk of 32; S: quad
    const int i0 = 32 * q;

    __shared__ __align__(16) float stA[144], stB[144];  // V alpha ping-pong
    __shared__ __align__(16) __bf16 sbf[2][NN];         // S state (bf16) dbl-buf
    __shared__ unsigned char bp_lds[TT * NN];           // V: 64 KB backpointers
    __shared__ unsigned char tags_lds[TT];
    __shared__ unsigned char map_lds[8 * NN];
    __shared__ int entry_sh[8];
    __shared__ int msk[TT];
    __shared__ float piv[2];
    __shared__ float sfin[NN];
    __shared__ float wsum[8];
    __shared__ float llnorm_sh;
    __shared__ int misc[2];                             // [0]=lastTag [1]=kacc

    msk[tid] = mask[b * TT + tid];

    const float* emb = em + (size_t)b * TT * NN;

    if (isV) {
        float4 c0, c1, c2, c3, c4, c5, c6, c7;
        {
            const float* tc = trans + (size_t)i0 * NN + j;
            #define LDC(cc, u) cc.x = tc[(4*u+0)*NN]; cc.y = tc[(4*u+1)*NN]; \
                               cc.z = tc[(4*u+2)*NN]; cc.w = tc[(4*u+3)*NN];
            LDC(c0, 0) LDC(c1, 1) LDC(c2, 2) LDC(c3, 3)
            LDC(c4, 4) LDC(c5, 5) LDC(c6, 6) LDC(c7, 7)
            #undef LDC
        }
        float st = 0.f;
        {
            float a0 = emb[j];
            st = a0;
            if (l < 16) stA[padidx(j)] = a0;
        }
        float e_next = emb[NN + j];
        __syncthreads();

        const float4* apA = (const float4*)(stA + 36 * q);
        const float4* apB = (const float4*)(stB + 36 * q);

        auto VSTEP = [&](int t, const float4* ap, float* dst) {
            const float e_cur = e_next;
            if (t + 1 < TT) e_next = emb[(size_t)(t + 1) * NN + j];
            const int m = msk[t];
            float4 v0 = ap[0], v1 = ap[1], v2 = ap[2], v3 = ap[3],
                   v4 = ap[4], v5 = ap[5], v6 = ap[6], v7 = ap[7];
            float m0 = -INFINITY, m1 = -INFINITY, m2 = -INFINITY, m3 = -INFINITY;
            int u0 = 0, u1 = 0, u2 = 0, u3 = 0;
            #define CH(vv, cc, u) { \
                float a = vv.x + cc.x; u0 = (a > m0) ? u : u0; m0 = fmaxf(m0, a); \
                float bq = vv.y + cc.y; u1 = (bq > m1) ? u : u1; m1 = fmaxf(m1, bq); \
                float c = vv.z + cc.z; u2 = (c > m2) ? u : u2; m2 = fmaxf(m2, c); \
                float d = vv.w + cc.w; u3 = (d > m3) ? u : u3; m3 = fmaxf(m3, d); }
            CH(v0, c0, 0) CH(v1, c1, 1) CH(v2, c2, 2) CH(v3, c3, 3)
            CH(v4, c4, 4) CH(v5, c5, 5) CH(v6, c6, 6) CH(v7, c7, 7)
            #undef CH
            float bv = m0; int bx = i0 + 4 * u0;
            { int id = i0 + 4*u1 + 1; if (m1 > bv || (m1 == bv && id < bx)) { bv = m1; bx = id; } }
            { int id = i0 + 4*u2 + 2; if (m2 > bv || (m2 == bv && id < bx)) { bv = m2; bx = id; } }
            { int id = i0 + 4*u3 + 3; if (m3 > bv || (m3 == bv && id < bx)) { bv = m3; bx = id; } }
            #pragma unroll
            for (int off = 16; off <= 32; off <<= 1) {
                float ov = __shfl_xor(bv, off);
                int oi = __shfl_xor(bx, off);
                if (ov > bv || (ov == bv && oi < bx)) { bv = ov; bx = oi; }
            }
            if (l < 16) {
                float an; int bp;
                if (m) { an = bv + e_cur; bp = bx; }   // plain add = reference-exact
                else   { an = st;         bp = j;  }   // identity bp when masked
                st = an;
                dst[padidx(j)] = an;
                bp_lds[t * NN + j] = (unsigned char)bp;
            }
            __syncthreads();
        };

        for (int t = 1; t < TT - 1; t += 2) {
            VSTEP(t, apA, stB);
            VSTEP(t + 1, apB, stA);
        }
        VSTEP(TT - 1, apA, stB);   // final alpha in stB

        if (w == 0) {   // last-tag argmax (exact, first-index ties)
            float a0 = stB[padidx(2 * l)], a1 = stB[padidx(2 * l + 1)];
            int tg = wave_argmax128(a0, a1, l);
            if (l == 0) { misc[0] = tg; tags_lds[TT - 1] = (unsigned char)tg; }
        }
        if (tid < 64) out_trans[b * 64 + tid] = trans[b * 64 + tid];  // folded copy
        __syncthreads();
        // Phase 1: each wave maps all 128 entry tags through its 64-step chunk.
        const int lo = 64 * w + 1;
        const int hi = (w == 7) ? (TT - 1) : (64 * w + 64);
        {
            int tA = 2 * l, tB = 2 * l + 1;
            for (int t = hi; t >= lo; --t) {
                tA = bp_lds[t * NN + tA];
                tB = bp_lds[t * NN + tB];
            }
            map_lds[w * NN + 2 * l]     = (unsigned char)tA;
            map_lds[w * NN + 2 * l + 1] = (unsigned char)tB;
        }
        __syncthreads();
        // Phase 2: compose chunk maps -> true entry tag per chunk.
        if (tid == 0) {
            int e = misc[0];
            entry_sh[7] = e;
            for (int c = 7; c >= 1; --c) { e = map_lds[c * NN + e]; entry_sh[c - 1] = e; }
        }
        __syncthreads();
        // Phase 3: re-trace each chunk from its true entry.
        if (l == 0) {
            int tg = entry_sh[w];
            for (int t = hi; t >= lo; --t) {
                tg = bp_lds[t * NN + tg];
                tags_lds[t - 1] = (unsigned char)tg;
            }
        }
        __syncthreads();
        outp[(size_t)b * TT + tid] = (float)tags_lds[tid];
    } else {
        bf16x8 Bf[4];
        #pragma unroll
        for (int kc = 0; kc < 4; ++kc) {
            #pragma unroll
            for (int jj = 0; jj < 8; ++jj) {
                int row = kc * 32 + q * 8 + jj;
                Bf[kc][jj] = to_bf16(__expf(trans[(size_t)row * NN + j]));
            }
        }
        float ss = __expf(emb[j]);
        int kacc = 0;
        if (l < 16) sbf[0][j] = to_bf16(ss);
        if (tid == 0) piv[0] = ss;
        float e_next = emb[NN + j];
        __syncthreads();

        for (int t = 1; t < TT; ++t) {
            const float e_cur = e_next;
            if (t + 1 < TT) e_next = emb[(size_t)(t + 1) * NN + j];
            const int m = msk[t];
            const int p = (t - 1) & 1, qb = t & 1;
            if (m) {
                const __bf16* sp = sbf[p];
                floatx4 acc = {0.f, 0.f, 0.f, 0.f};
                #pragma unroll
                for (int kc = 0; kc < 4; ++kc) {
                    bf16x8 a = *(const bf16x8*)(sp + kc * 32 + q * 8);
                    acc = __builtin_amdgcn_mfma_f32_16x16x32_bf16(a, Bf[kc], acc, 0, 0, 0);
                }
                float dot = acc[0];                    // rows identical -> regs equal
                const float pv = piv[p];
                const int k = (int)(__float_as_uint(pv) >> 23) - 127;
                const float scale = __uint_as_float((unsigned)(127 - k) << 23);  // 2^-k
                ss = dot * scale * __expf(e_cur);
                if (tid == 0) kacc += k;
            }
            if (l < 16) sbf[qb][j] = to_bf16(ss);
            if (tid == 0) piv[qb] = ss;
            __syncthreads();
        }

        if (l < 16) sfin[j] = ss;
        if (tid == 0) misc[1] = kacc;
        __syncthreads();
        if (w == 0) {
            float v = sfin[2 * l] + sfin[2 * l + 1];
            v = wave_sum64(v);
            if (l == 0) llnorm_sh = __logf(v) + (float)misc[1] * LN2F;
        }
        // Folded gold-path score: one t per thread (TT == blockDim).
        float acc = 0.f;
        {
            int tg = gtags[b * TT + tid];
            float mf = (float)msk[tid];
            acc = emb[(size_t)tid * NN + tg] * mf;
            if (tid >= 1) {
                int tp = gtags[b * TT + tid - 1];
                acc += trans[tp * NN + tg] * mf;
            }
        }
        acc = wave_sum64(acc);
        if (l == 0) wsum[w] = acc;
        __syncthreads();
        if (tid == 0) {
            float s = 0.f;
            #pragma unroll
            for (int i = 0; i < 8; ++i) s += wsum[i];
            out_ll[b] = s - llnorm_sh;
        }
    }
}

extern "C" void kernel_launch(void* const* d_in, const int* in_sizes, int n_in,
                              void* d_out, int out_size, void* d_ws, size_t ws_size,
                              hipStream_t stream) {
    const float* em = (const float*)d_in[0];
    const int* gtags = (const int*)d_in[1];
    const int* mask = (const int*)d_in[2];
    const float* trans = (const float*)d_in[3];

    float* out = (float*)d_out;
    float* out_ll = out;
    float* out_trans = out + BB;
    float* out_pred = out + BB + NN * NN;

    hipLaunchKernelGGL(fwd_kernel, dim3(2 * BB), dim3(512), 0, stream,
                       em, gtags, mask, trans, out_ll, out_trans, out_pred);
}

// Round 10
// 500.219 us; speedup vs baseline: 1.3497x; 1.3497x over previous
//
#include <hip/hip_runtime.h>
#include <cmath>

#define BB 256
#define TT 512
#define NN 128
#define LN2F 0.6931471805599453f

typedef __bf16 bf16x8 __attribute__((ext_vector_type(8)));
typedef float floatx4 __attribute__((ext_vector_type(4)));

__device__ __forceinline__ float wave_max64(float v) {
    #pragma unroll
    for (int off = 32; off; off >>= 1) v = fmaxf(v, __shfl_xor(v, off));
    return v;
}
__device__ __forceinline__ float wave_sum64(float v) {
    #pragma unroll
    for (int off = 32; off; off >>= 1) v += __shfl_xor(v, off);
    return v;
}
// argmax over 128 values (lane l holds indices 2l, 2l+1); first-index tie-break.
__device__ __forceinline__ int wave_argmax128(float v0, float v1, int l) {
    float m = fmaxf(v0, v1);
    float wm = wave_max64(m);
    unsigned long long ball = __ballot(m == wm);
    int lane = __ffsll(ball) - 1;
    int idx = (v0 == wm) ? (2 * l) : (2 * l + 1);
    return __shfl(idx, lane);
}

__device__ __forceinline__ __bf16 to_bf16(float f) {   // RNE
    unsigned u = __float_as_uint(f);
    unsigned r = (u + 0x7FFFu + ((u >> 16) & 1u)) >> 16;
    union { unsigned short s; __bf16 b; } cv;
    cv.s = (unsigned short)r;
    return cv.b;
}

// DPP quad_perm cross-lane ops: VALU pipe, NOT the DS pipe.
// xor1 = quad_perm[1,0,3,2] = 0xB1; xor2 = quad_perm[2,3,0,1] = 0x4E.
__device__ __forceinline__ float dpp_xor1_f(float v) {
    return __int_as_float(__builtin_amdgcn_mov_dpp(__float_as_int(v), 0xB1, 0xF, 0xF, true));
}
__device__ __forceinline__ int dpp_xor1_i(int v) {
    return __builtin_amdgcn_mov_dpp(v, 0xB1, 0xF, 0xF, true);
}
__device__ __forceinline__ float dpp_xor2_f(float v) {
    return __int_as_float(__builtin_amdgcn_mov_dpp(__float_as_int(v), 0x4E, 0xF, 0xF, true));
}
__device__ __forceinline__ int dpp_xor2_i(int v) {
    return __builtin_amdgcn_mov_dpp(v, 0x4E, 0xF, 0xF, true);
}

// Padded state layout: 32-float chunk c starts at word 36c (bank offset 4c).
__device__ __forceinline__ int padidx(int i) { return 36 * (i >> 5) + (i & 31); }

// Forward. grid = 2*BB, 512-thread blocks (8 waves), 2 blocks/CU (V_b + S_b).
// MODEL (fits R0-R9): V chain is DS-PIPE-bound: per step/CU ~768cy b128 reads
// + ~384cy ds_swizzle shuffles + ~150cy writes = ~1300 of the 2232cy interval.
// (VALUBusy 67% is per-CU any-SIMD; per-SIMD VALU is only ~700cy. R9's V+V =
// 2x1300 DS demand -> interval 2972 ✓. R8's 2x waves = 2x DS instr ✓.)
// THIS ROUND: (1) col lanes = quad {4k..4k+3} (jv=(l>>2)+16w, qv=l&3) so the
// 4-lane reduce runs on DPP quad_perm (VALU) — removes ALL per-step swizzles
// from the DS pipe. Bank profile unchanged (4 chunk-groups x 4 banks, 16-way
// broadcast). (2) s_setprio(1) on V waves (role-diverse vs S, T5).
__global__ __launch_bounds__(512, 4) void fwd_kernel(
        const float* __restrict__ em, const int* __restrict__ gtags,
        const int* __restrict__ mask, const float* __restrict__ trans,
        float* __restrict__ out_ll, float* __restrict__ out_trans,
        float* __restrict__ outp) {
    const int bi = blockIdx.x;
    const bool isV = bi < BB;
    const int b = isV ? bi : bi - BB;
    const int tid = threadIdx.x;
    const int w = tid >> 6;
    const int l = tid & 63;

    __shared__ __align__(16) float stA[144], stB[144];  // V alpha ping-pong
    __shared__ __align__(16) __bf16 sbf[2][NN];         // S state (bf16) dbl-buf
    __shared__ unsigned char bp_lds[TT * NN];           // V: 64 KB backpointers
    __shared__ unsigned char tags_lds[TT];
    __shared__ unsigned char map_lds[8 * NN];
    __shared__ int entry_sh[8];
    __shared__ int msk[TT];
    __shared__ float piv[2];
    __shared__ float sfin[NN];
    __shared__ float wsum[8];
    __shared__ float llnorm_sh;
    __shared__ int misc[2];                             // [0]=lastTag [1]=kacc

    msk[tid] = mask[b * TT + tid];

    const float* emb = em + (size_t)b * TT * NN;

    if (isV) {
        __builtin_amdgcn_s_setprio(1);
        const int jv = (l >> 2) + 16 * w;   // column: quad 4k..4k+3 owns col
        const int qv = l & 3;               // i-chunk of 32
        const int i0 = 32 * qv;
        float4 c0, c1, c2, c3, c4, c5, c6, c7;
        {
            const float* tc = trans + (size_t)i0 * NN + jv;
            #define LDC(cc, u) cc.x = tc[(4*u+0)*NN]; cc.y = tc[(4*u+1)*NN]; \
                               cc.z = tc[(4*u+2)*NN]; cc.w = tc[(4*u+3)*NN];
            LDC(c0, 0) LDC(c1, 1) LDC(c2, 2) LDC(c3, 3)
            LDC(c4, 4) LDC(c5, 5) LDC(c6, 6) LDC(c7, 7)
            #undef LDC
        }
        float st = 0.f;
        {
            float a0 = emb[jv];
            st = a0;
            if ((l & 3) == 0) stA[padidx(jv)] = a0;
        }
        float e_next = emb[NN + jv];
        __syncthreads();

        const float4* apA = (const float4*)(stA + 36 * qv);
        const float4* apB = (const float4*)(stB + 36 * qv);

        auto VSTEP = [&](int t, const float4* ap, float* dst) {
            const float e_cur = e_next;
            if (t + 1 < TT) e_next = emb[(size_t)(t + 1) * NN + jv];
            const int m = msk[t];
            float4 v0 = ap[0], v1 = ap[1], v2 = ap[2], v3 = ap[3],
                   v4 = ap[4], v5 = ap[5], v6 = ap[6], v7 = ap[7];
            float m0 = -INFINITY, m1 = -INFINITY, m2 = -INFINITY, m3 = -INFINITY;
            int u0 = 0, u1 = 0, u2 = 0, u3 = 0;
            #define CH(vv, cc, u) { \
                float a = vv.x + cc.x; u0 = (a > m0) ? u : u0; m0 = fmaxf(m0, a); \
                float bq = vv.y + cc.y; u1 = (bq > m1) ? u : u1; m1 = fmaxf(m1, bq); \
                float c = vv.z + cc.z; u2 = (c > m2) ? u : u2; m2 = fmaxf(m2, c); \
                float d = vv.w + cc.w; u3 = (d > m3) ? u : u3; m3 = fmaxf(m3, d); }
            CH(v0, c0, 0) CH(v1, c1, 1) CH(v2, c2, 2) CH(v3, c3, 3)
            CH(v4, c4, 4) CH(v5, c5, 5) CH(v6, c6, 6) CH(v7, c7, 7)
            #undef CH
            float bv = m0; int bx = i0 + 4 * u0;
            { int id = i0 + 4*u1 + 1; if (m1 > bv || (m1 == bv && id < bx)) { bv = m1; bx = id; } }
            { int id = i0 + 4*u2 + 2; if (m2 > bv || (m2 == bv && id < bx)) { bv = m2; bx = id; } }
            { int id = i0 + 4*u3 + 3; if (m3 > bv || (m3 == bv && id < bx)) { bv = m3; bx = id; } }
            // Quad reduce on the VALU pipe (DPP), freeing the DS pipe.
            {
                float ov = dpp_xor1_f(bv); int oi = dpp_xor1_i(bx);
                if (ov > bv || (ov == bv && oi < bx)) { bv = ov; bx = oi; }
                ov = dpp_xor2_f(bv); oi = dpp_xor2_i(bx);
                if (ov > bv || (ov == bv && oi < bx)) { bv = ov; bx = oi; }
            }
            if ((l & 3) == 0) {
                float an; int bp;
                if (m) { an = bv + e_cur; bp = bx; }   // plain add = reference-exact
                else   { an = st;         bp = jv; }   // identity bp when masked
                st = an;
                dst[padidx(jv)] = an;
                bp_lds[t * NN + jv] = (unsigned char)bp;
            }
            __syncthreads();
        };

        for (int t = 1; t < TT - 1; t += 2) {
            VSTEP(t, apA, stB);
            VSTEP(t + 1, apB, stA);
        }
        VSTEP(TT - 1, apA, stB);   // final alpha in stB

        if (w == 0) {   // last-tag argmax (exact, first-index ties)
            float a0 = stB[padidx(2 * l)], a1 = stB[padidx(2 * l + 1)];
            int tg = wave_argmax128(a0, a1, l);
            if (l == 0) { misc[0] = tg; tags_lds[TT - 1] = (unsigned char)tg; }
        }
        if (tid < 64) out_trans[b * 64 + tid] = trans[b * 64 + tid];  // folded copy
        __syncthreads();
        // Phase 1: each wave maps all 128 entry tags through its 64-step chunk.
        const int lo = 64 * w + 1;
        const int hi = (w == 7) ? (TT - 1) : (64 * w + 64);
        {
            int tA = 2 * l, tB = 2 * l + 1;
            for (int t = hi; t >= lo; --t) {
                tA = bp_lds[t * NN + tA];
                tB = bp_lds[t * NN + tB];
            }
            map_lds[w * NN + 2 * l]     = (unsigned char)tA;
            map_lds[w * NN + 2 * l + 1] = (unsigned char)tB;
        }
        __syncthreads();
        // Phase 2: compose chunk maps -> true entry tag per chunk.
        if (tid == 0) {
            int e = misc[0];
            entry_sh[7] = e;
            for (int c = 7; c >= 1; --c) { e = map_lds[c * NN + e]; entry_sh[c - 1] = e; }
        }
        __syncthreads();
        // Phase 3: re-trace each chunk from its true entry.
        if (l == 0) {
            int tg = entry_sh[w];
            for (int t = hi; t >= lo; --t) {
                tg = bp_lds[t * NN + tg];
                tags_lds[t - 1] = (unsigned char)tg;
            }
        }
        __syncthreads();
        outp[(size_t)b * TT + tid] = (float)tags_lds[tid];
        __builtin_amdgcn_s_setprio(0);
    } else {
        const int j = (l & 15) + 16 * w;
        const int q = l >> 4;
        bf16x8 Bf[4];
        #pragma unroll
        for (int kc = 0; kc < 4; ++kc) {
            #pragma unroll
            for (int jj = 0; jj < 8; ++jj) {
                int row = kc * 32 + q * 8 + jj;
                Bf[kc][jj] = to_bf16(__expf(trans[(size_t)row * NN + j]));
            }
        }
        float ss = __expf(emb[j]);
        int kacc = 0;
        if (l < 16) sbf[0][j] = to_bf16(ss);
        if (tid == 0) piv[0] = ss;
        float e_next = emb[NN + j];
        __syncthreads();

        for (int t = 1; t < TT; ++t) {
            const float e_cur = e_next;
            if (t + 1 < TT) e_next = emb[(size_t)(t + 1) * NN + j];
            const int m = msk[t];
            const int p = (t - 1) & 1, qb = t & 1;
            if (m) {
                const __bf16* sp = sbf[p];
                floatx4 acc = {0.f, 0.f, 0.f, 0.f};
                #pragma unroll
                for (int kc = 0; kc < 4; ++kc) {
                    bf16x8 a = *(const bf16x8*)(sp + kc * 32 + q * 8);
                    acc = __builtin_amdgcn_mfma_f32_16x16x32_bf16(a, Bf[kc], acc, 0, 0, 0);
                }
                float dot = acc[0];                    // rows identical -> regs equal
                const float pv = piv[p];
                const int k = (int)(__float_as_uint(pv) >> 23) - 127;
                const float scale = __uint_as_float((unsigned)(127 - k) << 23);  // 2^-k
                ss = dot * scale * __expf(e_cur);
                if (tid == 0) kacc += k;
            }
            if (l < 16) sbf[qb][j] = to_bf16(ss);
            if (tid == 0) piv[qb] = ss;
            __syncthreads();
        }

        if (l < 16) sfin[j] = ss;
        if (tid == 0) misc[1] = kacc;
        __syncthreads();
        if (w == 0) {
            float v = sfin[2 * l] + sfin[2 * l + 1];
            v = wave_sum64(v);
            if (l == 0) llnorm_sh = __logf(v) + (float)misc[1] * LN2F;
        }
        // Folded gold-path score: one t per thread (TT == blockDim).
        float acc = 0.f;
        {
            int tg = gtags[b * TT + tid];
            float mf = (float)msk[tid];
            acc = emb[(size_t)tid * NN + tg] * mf;
            if (tid >= 1) {
                int tp = gtags[b * TT + tid - 1];
                acc += trans[tp * NN + tg] * mf;
            }
        }
        acc = wave_sum64(acc);
        if (l == 0) wsum[w] = acc;
        __syncthreads();
        if (tid == 0) {
            float s = 0.f;
            #pragma unroll
            for (int i = 0; i < 8; ++i) s += wsum[i];
            out_ll[b] = s - llnorm_sh;
        }
    }
}

extern "C" void kernel_launch(void* const* d_in, const int* in_sizes, int n_in,
                              void* d_out, int out_size, void* d_ws, size_t ws_size,
                              hipStream_t stream) {
    const float* em = (const float*)d_in[0];
    const int* gtags = (const int*)d_in[1];
    const int* mask = (const int*)d_in[2];
    const float* trans = (const float*)d_in[3];

    float* out = (float*)d_out;
    float* out_ll = out;
    float* out_trans = out + BB;
    float* out_pred = out + BB + NN * NN;

    hipLaunchKernelGGL(fwd_kernel, dim3(2 * BB), dim3(512), 0, stream,
                       em, gtags, mask, trans, out_ll, out_trans, out_pred);
}